// Round 3
// baseline (216.353 us; speedup 1.0000x reference)
//
#include <hip/hip_runtime.h>

#define NPIX 65536
#define BN_EPS 1e-3f

typedef __attribute__((ext_vector_type(8))) short bf16x8;
typedef __attribute__((ext_vector_type(4))) float f32x4;

__device__ inline unsigned short f2b(float f) {
    unsigned int u = __float_as_uint(f);
    unsigned int r = (u + 0x7fffu + ((u >> 16) & 1u)) >> 16;
    return (unsigned short)r;
}
__device__ inline float b2f(unsigned short h) {
    return __uint_as_float(((unsigned int)h) << 16);
}

// ---------------------------------------------------------------------------
// k_prep: Bt[n][k] = bf16 of (n<256 ? Wi[k][n] : Wr[k][n-256])   [320,256]
//         Wst[n][k] = bf16 of Ws[k][n]                            [144,64]
// ---------------------------------------------------------------------------
__global__ void k_prep(const float* __restrict__ Wi, const float* __restrict__ Wr,
                       const float* __restrict__ Ws,
                       unsigned short* __restrict__ Bt, unsigned short* __restrict__ Wst) {
    int t = blockIdx.x * 256 + threadIdx.x;
    if (t < 320 * 256) {
        int n = t >> 8, k = t & 255;
        float v = (n < 256) ? Wi[k * 256 + n] : Wr[k * 64 + (n - 256)];
        Bt[t] = f2b(v);
    } else {
        int t2 = t - 320 * 256;
        if (t2 < 144 * 64) {
            int n = t2 >> 6, k = t2 & 63;
            Wst[t2] = f2b(Ws[k * 144 + n]);
        }
    }
}

// ---------------------------------------------------------------------------
// k12: fused  xi = x@Wi+bi (bf16->HBM),  r = relu(BN(x@Wr+br)) (LDS only),
//             w = r@Ws+bs (bf16->HBM).
// M-tile 32 px, 256 thr / 4 waves. Main GEMM: N=320 (20 n-tiles), wave wv
// covers nt wv*5..wv*5+4, 2 m-tiles -> acc=40 VGPR. Explicit next-kc B
// prefetch to hide L2 latency. Then barrier + tiny w-GEMM from LDS r.
// ---------------------------------------------------------------------------
#define APAD12 264   // 256+8 u16 pad: 2-way (free) b128 LDS pattern
__global__ __launch_bounds__(256, 3) void k12(
    const float* __restrict__ x, const unsigned short* __restrict__ Bt,
    const float* __restrict__ bi, const float* __restrict__ br,
    const float* __restrict__ gamma, const float* __restrict__ beta,
    const float* __restrict__ mean, const float* __restrict__ var,
    const unsigned short* __restrict__ Wst, const float* __restrict__ bs,
    unsigned short* __restrict__ xi_b, unsigned short* __restrict__ w_b)
{
    __shared__ unsigned short As[32 * APAD12];   // 16.9 KB
    __shared__ unsigned short Rs[32 * 72];       // 4.6 KB (pad 72)
    const int tid = threadIdx.x;
    const int p0 = blockIdx.x * 32;

    // stage A: 32 rows x 256 ch, fp32 -> bf16
    {
        const float* xs = x + (long long)p0 * 256;
        for (int i = tid * 4; i < 32 * 256; i += 1024) {
            float4 v = *(const float4*)&xs[i];
            int m = i >> 8, k = i & 255;
            unsigned short* d = &As[m * APAD12 + k];
            d[0] = f2b(v.x); d[1] = f2b(v.y); d[2] = f2b(v.z); d[3] = f2b(v.w);
        }
    }
    __syncthreads();

    const int wv = tid >> 6;
    const int lane = tid & 63;
    const int col = lane & 15;
    const int quad = lane >> 4;
    const int nt0 = wv * 5;

    f32x4 acc[2][5];
#pragma unroll
    for (int i = 0; i < 2; ++i)
#pragma unroll
        for (int j = 0; j < 5; ++j) acc[i][j] = (f32x4){0.f, 0.f, 0.f, 0.f};

    // B row base pointers (per nt)
    const unsigned short* bp[5];
#pragma unroll
    for (int nt = 0; nt < 5; ++nt)
        bp[nt] = &Bt[((nt0 + nt) * 16 + col) * 256];

    // preload kc=0 B frags
    bf16x8 bc[5];
#pragma unroll
    for (int nt = 0; nt < 5; ++nt)
        bc[nt] = *(const bf16x8*)&bp[nt][quad * 8];

#pragma unroll
    for (int kc = 0; kc < 8; ++kc) {
        const int kb  = kc * 32 + quad * 8;
        const int kbn = (kc < 7) ? kb + 32 : kb;   // prefetch next (or harmless reload)
        bf16x8 bn[5];
#pragma unroll
        for (int nt = 0; nt < 5; ++nt)
            bn[nt] = *(const bf16x8*)&bp[nt][kbn];
        bf16x8 a0 = *(const bf16x8*)&As[(col) * APAD12 + kb];
        bf16x8 a1 = *(const bf16x8*)&As[(16 + col) * APAD12 + kb];
#pragma unroll
        for (int nt = 0; nt < 5; ++nt) {
            acc[0][nt] = __builtin_amdgcn_mfma_f32_16x16x32_bf16(a0, bc[nt], acc[0][nt], 0, 0, 0);
            acc[1][nt] = __builtin_amdgcn_mfma_f32_16x16x32_bf16(a1, bc[nt], acc[1][nt], 0, 0, 0);
        }
#pragma unroll
        for (int nt = 0; nt < 5; ++nt) bc[nt] = bn[nt];
    }

    // epilogue: D row = quad*4+rg, col = col.  n<256 -> xi store; else r to LDS.
#pragma unroll
    for (int nt = 0; nt < 5; ++nt) {
        const int n = (nt0 + nt) * 16 + col;
        if (n < 256) {
            const float bv = bi[n];
#pragma unroll
            for (int mt = 0; mt < 2; ++mt) {
                const int prow = p0 + mt * 16 + quad * 4;
#pragma unroll
                for (int rg = 0; rg < 4; ++rg)
                    xi_b[(long long)(prow + rg) * 256 + n] = f2b(acc[mt][nt][rg] + bv);
            }
        } else {
            const int d = n - 256;
            const float brd = br[d], md = mean[d], bt = beta[d];
            const float sc = gamma[d] * rsqrtf(var[d] + BN_EPS);
#pragma unroll
            for (int mt = 0; mt < 2; ++mt) {
                const int mrow = mt * 16 + quad * 4;
#pragma unroll
                for (int rg = 0; rg < 4; ++rg) {
                    float v = (acc[mt][nt][rg] + brd - md) * sc + bt;
                    Rs[(mrow + rg) * 72 + d] = f2b(fmaxf(v, 0.f));
                }
            }
        }
    }
    __syncthreads();

    // ---- w GEMM: [32,144] = r[32,64] @ Wst^T (+bs) ----
    {
        const int mt_w = wv & 1;
        const int jn0  = (wv >> 1) ? 5 : 0;
        const int jcnt = (wv >> 1) ? 4 : 5;
        f32x4 wacc[5];
#pragma unroll
        for (int j = 0; j < 5; ++j) wacc[j] = (f32x4){0.f, 0.f, 0.f, 0.f};
#pragma unroll
        for (int kc = 0; kc < 2; ++kc) {
            const int kb = kc * 32 + quad * 8;
            bf16x8 ra = *(const bf16x8*)&Rs[(mt_w * 16 + col) * 72 + kb];
#pragma unroll
            for (int j = 0; j < 5; ++j) {
                if (j < jcnt) {
                    bf16x8 wb = *(const bf16x8*)&Wst[((jn0 + j) * 16 + col) * 64 + kb];
                    wacc[j] = __builtin_amdgcn_mfma_f32_16x16x32_bf16(ra, wb, wacc[j], 0, 0, 0);
                }
            }
        }
#pragma unroll
        for (int j = 0; j < 5; ++j) {
            if (j < jcnt) {
                const int n = (jn0 + j) * 16 + col;
                const float bv = bs[n];
#pragma unroll
                for (int rg = 0; rg < 4; ++rg)
                    w_b[(long long)(p0 + mt_w * 16 + quad * 4 + rg) * 144 + n] =
                        f2b(wacc[j][rg] + bv);
            }
        }
    }
}

// ---------------------------------------------------------------------------
// k3: gather. 32 px (row-aligned) per block, 512 thr; thread = (pixel p, grp g).
// Halo 3 x 34 rows of bf16 xi in LDS; w tile staged as fp32 (no unpack in the
// inner fma). Contiguous-run trick: flat idx = g*144+f2*9+kk spans at most two
// channel runs -> 18 aligned ds_read_b128 per thread.
// ---------------------------------------------------------------------------
#define XR3 264
#define NROW3 102           // 3*34 halo rows
__global__ __launch_bounds__(512, 4) void k3_gather(
    const unsigned short* __restrict__ xi_b, const unsigned short* __restrict__ w_b,
    float* __restrict__ out)
{
    __shared__ unsigned short smx[NROW3 * XR3];  // 53.9 KB
    __shared__ float smw[32 * 148];              // 18.9 KB
    const int tid = threadIdx.x;
    const int pp0 = blockIdx.x * 32;
    const int bb = pp0 >> 14;
    const int h  = (pp0 >> 7) & 127;
    const int w0 = pp0 & 127;

    // stage halo (3264 int4 granules) + w tile fp32 (576 granules)
    for (int t = tid; t < NROW3 * 32 + 576; t += 512) {
        if (t < NROW3 * 32) {
            const int row = t >> 5, gi = t & 31;
            const int ki = row / 34, kjc = row - ki * 34;
            const int sh = h + ki - 1;
            const int sw = w0 + kjc - 1;
            int4 v = {0, 0, 0, 0};
            if ((unsigned)sh < 128u && (unsigned)sw < 128u)
                v = *(const int4*)&xi_b[(long long)((bb * 128 + sh) * 128 + sw) * 256 + gi * 8];
            *(int4*)&smx[row * XR3 + gi * 8] = v;
        } else {
            const int t2 = t - NROW3 * 32;       // 0..575
            const int p = t2 / 18, rem = t2 - p * 18;
            const int n0 = rem * 8;
            int4 v = *(const int4*)&w_b[((long long)(pp0 + p)) * 144 + n0];
            const unsigned short* u = (const unsigned short*)&v;
            float* d = &smw[p * 148 + n0];
#pragma unroll
            for (int i = 0; i < 8; ++i) d[i] = b2f(u[i]);
        }
    }
    __syncthreads();

    const int g = tid & 15;
    const int p = tid >> 4;   // 0..31

    const int idx0 = g * 144;
    const int kp0  = idx0 >> 8;
    const int c0   = idx0 & 255;              // multiple of 16
    int len1 = 256 - c0; if (len1 > 144) len1 = 144;
    const int kp1  = kp0 + 1;
    const int base0 = ((kp0 / 3) * 34 + (kp0 % 3) + p) * XR3 + c0;
    const int base1 = (kp1 <= 8) ? (((kp1 / 3) * 34 + (kp1 % 3) + p) * XR3) : 0;

    float wf[9];
#pragma unroll
    for (int kk = 0; kk < 9; ++kk)
        wf[kk] = smw[p * 148 + g * 9 + kk];

    float res[16];

    // ---- half 1: e in [0,72) -> xv blocks 0..8, f2 0..7 ----
    {
        int4 xv[9];
#pragma unroll
        for (int i = 0; i < 9; ++i) {
            const int e = i * 8;
            const int addr = (e < len1) ? (base0 + e) : (base1 + (e - len1));
            xv[i] = *(const int4*)&smx[addr];
        }
#pragma unroll
        for (int f2 = 0; f2 < 8; ++f2) {
            float a = 0.f;
#pragma unroll
            for (int kk = 0; kk < 9; ++kk) {
                const int e = f2 * 9 + kk;
                const int word = ((const int*)&xv[e >> 3])[(e >> 1) & 3];
                const unsigned short u = (e & 1) ? (unsigned short)(((unsigned)word) >> 16)
                                                 : (unsigned short)(word & 0xffff);
                a += wf[kk] * b2f(u);
            }
            res[f2] = a;
        }
    }
    // ---- half 2: e in [72,144) -> xv blocks 9..17, f2 8..15 ----
    {
        int4 xv[9];
#pragma unroll
        for (int i = 9; i < 18; ++i) {
            const int e = i * 8;
            const int addr = (e < len1) ? (base0 + e) : (base1 + (e - len1));
            xv[i - 9] = *(const int4*)&smx[addr];
        }
#pragma unroll
        for (int f2 = 8; f2 < 16; ++f2) {
            float a = 0.f;
#pragma unroll
            for (int kk = 0; kk < 9; ++kk) {
                const int e = f2 * 9 + kk;
                const int i = (e >> 3) - 9;
                const int word = ((const int*)&xv[i])[(e >> 1) & 3];
                const unsigned short u = (e & 1) ? (unsigned short)(((unsigned)word) >> 16)
                                                 : (unsigned short)(word & 0xffff);
                a += wf[kk] * b2f(u);
            }
            res[f2] = a;
        }
    }

    const long long orow = ((long long)pp0 + p) * 256 + g * 16;
#pragma unroll
    for (int q = 0; q < 4; ++q) {
        float4 o = {res[q * 4 + 0], res[q * 4 + 1], res[q * 4 + 2], res[q * 4 + 3]};
        *(float4*)&out[orow + q * 4] = o;
    }
}

// ---------------------------------------------------------------------------
extern "C" void kernel_launch(void* const* d_in, const int* in_sizes, int n_in,
                              void* d_out, int out_size, void* d_ws, size_t ws_size,
                              hipStream_t stream) {
    const float* x     = (const float*)d_in[0];
    const float* Wr    = (const float*)d_in[1];
    const float* br    = (const float*)d_in[2];
    const float* gamma = (const float*)d_in[3];
    const float* beta  = (const float*)d_in[4];
    const float* mean  = (const float*)d_in[5];
    const float* var   = (const float*)d_in[6];
    const float* Ws    = (const float*)d_in[7];
    const float* bs    = (const float*)d_in[8];
    const float* Wi    = (const float*)d_in[9];
    const float* bi    = (const float*)d_in[10];
    float* out = (float*)d_out;

    // workspace layout (bytes, 16B-aligned)
    unsigned char* ws = (unsigned char*)d_ws;
    unsigned short* xi_b = (unsigned short*)(ws + 0);            // 65536*256*2 = 33,554,432
    unsigned short* w_b  = (unsigned short*)(ws + 33554432);     // 65536*144*2 = 18,874,368
    unsigned short* Bt   = (unsigned short*)(ws + 52428800);     // 320*256*2   =    163,840
    unsigned short* Wst  = (unsigned short*)(ws + 52592640);     // 144*64*2    =     18,432

    k_prep<<<dim3(356), dim3(256), 0, stream>>>(Wi, Wr, Ws, Bt, Wst);
    k12<<<dim3(NPIX / 32), dim3(256), 0, stream>>>(
        x, Bt, bi, br, gamma, beta, mean, var, Wst, bs, xi_b, w_b);
    k3_gather<<<dim3(NPIX / 32), dim3(512), 0, stream>>>(xi_b, w_b, out);
}

// Round 4
// 207.021 us; speedup vs baseline: 1.0451x; 1.0451x over previous
//
#include <hip/hip_runtime.h>

#define NPIX 65536
#define BN_EPS 1e-3f

typedef __attribute__((ext_vector_type(8))) short bf16x8;
typedef __attribute__((ext_vector_type(4))) float f32x4;

__device__ inline unsigned short f2b(float f) {
    unsigned int u = __float_as_uint(f);
    unsigned int r = (u + 0x7fffu + ((u >> 16) & 1u)) >> 16;
    return (unsigned short)r;
}
__device__ inline float b2f(unsigned short h) {
    return __uint_as_float(((unsigned int)h) << 16);
}

// ---------------------------------------------------------------------------
// k_prep: Bt[n][k] = bf16 of (n<256 ? Wi[k][n] : Wr[k][n-256])   [320,256]
//         Wst[n][k] = bf16 of Ws[k][n]                            [144,64]
// ---------------------------------------------------------------------------
__global__ void k_prep(const float* __restrict__ Wi, const float* __restrict__ Wr,
                       const float* __restrict__ Ws,
                       unsigned short* __restrict__ Bt, unsigned short* __restrict__ Wst) {
    int t = blockIdx.x * 256 + threadIdx.x;
    if (t < 320 * 256) {
        int n = t >> 8, k = t & 255;
        float v = (n < 256) ? Wi[k * 256 + n] : Wr[k * 64 + (n - 256)];
        Bt[t] = f2b(v);
    } else {
        int t2 = t - 320 * 256;
        if (t2 < 144 * 64) {
            int n = t2 >> 6, k = t2 & 63;
            Wst[t2] = f2b(Ws[k * 144 + n]);
        }
    }
}

// ---------------------------------------------------------------------------
// k12: fused  xi = x@Wi+bi,  r = relu(BN(x@Wr+br)) (LDS only),  w = r@Ws+bs.
// M-tile 64 px, 256 thr / 4 waves; wave wv: nt wv*5..wv*5+4, all 4 m-tiles
// (acc 4x5, 4:1 MFMA:B-load). ALL bf16 outputs leave via LDS transpose ->
// cooperative dwordx4 stores (no sub-dword global stores).
// LDS: As 64x264 u16 (33.8 KB, reused as xi/w transpose buffer) +
//      Rs 64x72 u16 (9.2 KB) = 43 KB -> 3 blocks/CU.
// ---------------------------------------------------------------------------
#define APAD12 264
__global__ __launch_bounds__(256, 3) void k12(
    const float* __restrict__ x, const unsigned short* __restrict__ Bt,
    const float* __restrict__ bi, const float* __restrict__ br,
    const float* __restrict__ gamma, const float* __restrict__ beta,
    const float* __restrict__ mean, const float* __restrict__ var,
    const unsigned short* __restrict__ Wst, const float* __restrict__ bs,
    unsigned short* __restrict__ xi_b, unsigned short* __restrict__ w_b)
{
    __shared__ unsigned short As[64 * APAD12];
    __shared__ unsigned short Rs[64 * 72];
    const int tid = threadIdx.x;
    const int p0 = blockIdx.x * 64;

    // ---- stage A: 64 rows x 256 ch, fp32 -> bf16, b64 LDS writes ----
    {
        const float* xs = x + (long long)p0 * 256;
        for (int i = tid * 4; i < 64 * 256; i += 1024) {
            float4 v = *(const float4*)&xs[i];
            int m = i >> 8, k = i & 255;
            uint2 pk;
            pk.x = (unsigned)f2b(v.x) | ((unsigned)f2b(v.y) << 16);
            pk.y = (unsigned)f2b(v.z) | ((unsigned)f2b(v.w) << 16);
            *(uint2*)&As[m * APAD12 + k] = pk;
        }
    }
    __syncthreads();

    const int wv = tid >> 6;
    const int lane = tid & 63;
    const int col = lane & 15;
    const int quad = lane >> 4;
    const int nt0 = wv * 5;

    f32x4 acc[4][5];
#pragma unroll
    for (int i = 0; i < 4; ++i)
#pragma unroll
        for (int j = 0; j < 5; ++j) acc[i][j] = (f32x4){0.f, 0.f, 0.f, 0.f};

    const unsigned short* bp[5];
#pragma unroll
    for (int nt = 0; nt < 5; ++nt)
        bp[nt] = &Bt[((nt0 + nt) * 16 + col) * 256];

    bf16x8 bc[5];
#pragma unroll
    for (int nt = 0; nt < 5; ++nt)
        bc[nt] = *(const bf16x8*)&bp[nt][quad * 8];

#pragma unroll
    for (int kc = 0; kc < 8; ++kc) {
        const int kb  = kc * 32 + quad * 8;
        const int kbn = (kc < 7) ? kb + 32 : kb;
        bf16x8 bn[5];
#pragma unroll
        for (int nt = 0; nt < 5; ++nt)
            bn[nt] = *(const bf16x8*)&bp[nt][kbn];
        bf16x8 a[4];
#pragma unroll
        for (int mt = 0; mt < 4; ++mt)
            a[mt] = *(const bf16x8*)&As[(mt * 16 + col) * APAD12 + kb];
#pragma unroll
        for (int mt = 0; mt < 4; ++mt)
#pragma unroll
            for (int nt = 0; nt < 5; ++nt)
                acc[mt][nt] = __builtin_amdgcn_mfma_f32_16x16x32_bf16(
                    a[mt], bc[nt], acc[mt][nt], 0, 0, 0);
#pragma unroll
        for (int nt = 0; nt < 5; ++nt) bc[nt] = bn[nt];
    }
    __syncthreads();   // A-tile dead; As becomes the transpose buffer

    // ---- epilogue 1: xi -> As (b16 LDS), r -> Rs (b16 LDS) ----
#pragma unroll
    for (int nt = 0; nt < 5; ++nt) {
        const int n = (nt0 + nt) * 16 + col;
        if (n < 256) {
            const float bv = bi[n];
#pragma unroll
            for (int mt = 0; mt < 4; ++mt) {
                const int mrow = mt * 16 + quad * 4;
#pragma unroll
                for (int rg = 0; rg < 4; ++rg)
                    As[(mrow + rg) * APAD12 + n] = f2b(acc[mt][nt][rg] + bv);
            }
        } else {
            const int d = n - 256;
            const float brd = br[d], md = mean[d], bt = beta[d];
            const float sc = gamma[d] * rsqrtf(var[d] + BN_EPS);
#pragma unroll
            for (int mt = 0; mt < 4; ++mt) {
                const int mrow = mt * 16 + quad * 4;
#pragma unroll
                for (int rg = 0; rg < 4; ++rg) {
                    float v = (acc[mt][nt][rg] + brd - md) * sc + bt;
                    Rs[(mrow + rg) * 72 + d] = f2b(fmaxf(v, 0.f));
                }
            }
        }
    }
    __syncthreads();

    // ---- coop store xi: 2048 dwordx4 granules, fully contiguous 32 KB ----
    {
        unsigned short* dst = xi_b + (long long)p0 * 256;
#pragma unroll
        for (int j = 0; j < 8; ++j) {
            const int gi = tid + j * 256;
            const int row = gi >> 5, c8 = gi & 31;
            int4 v = *(const int4*)&As[row * APAD12 + c8 * 8];
            *(int4*)&dst[gi * 8] = v;
        }
    }

    // ---- w GEMM: [64,144] = r[64,64] @ Wst^T (+bs); wave wv -> m-tile wv ----
    f32x4 wacc[9];
#pragma unroll
    for (int j = 0; j < 9; ++j) wacc[j] = (f32x4){0.f, 0.f, 0.f, 0.f};
#pragma unroll
    for (int kc = 0; kc < 2; ++kc) {
        const int kb = kc * 32 + quad * 8;
        bf16x8 ra = *(const bf16x8*)&Rs[(wv * 16 + col) * 72 + kb];
#pragma unroll
        for (int j = 0; j < 9; ++j) {
            bf16x8 wb = *(const bf16x8*)&Wst[(j * 16 + col) * 64 + kb];
            wacc[j] = __builtin_amdgcn_mfma_f32_16x16x32_bf16(ra, wb, wacc[j], 0, 0, 0);
        }
    }
    __syncthreads();   // xi coop-store reads of As done -> safe to overwrite

    // ---- epilogue 2: w -> As region [64][144] u16, then coop dwordx4 ----
    {
        unsigned short* Ww = As;
#pragma unroll
        for (int j = 0; j < 9; ++j) {
            const int n = j * 16 + col;
            const float bv = bs[n];
#pragma unroll
            for (int rg = 0; rg < 4; ++rg)
                Ww[(wv * 16 + quad * 4 + rg) * 144 + n] = f2b(wacc[j][rg] + bv);
        }
    }
    __syncthreads();
    {
        unsigned short* dst = w_b + (long long)p0 * 144;
#pragma unroll
        for (int j = 0; j < 5; ++j) {
            const int gi = tid + j * 256;   // 1152 granules of 16 B
            if (gi < 1152) {
                int4 v = *(const int4*)&As[gi * 8];
                *(int4*)&dst[gi * 8] = v;
            }
        }
    }
}

// ---------------------------------------------------------------------------
// k3: gather. 32 px (row-aligned) per block, 512 thr; thread = (pixel p, grp g).
// ---------------------------------------------------------------------------
#define XR3 264
#define NROW3 102
__global__ __launch_bounds__(512, 4) void k3_gather(
    const unsigned short* __restrict__ xi_b, const unsigned short* __restrict__ w_b,
    float* __restrict__ out)
{
    __shared__ unsigned short smx[NROW3 * XR3];
    __shared__ float smw[32 * 148];
    const int tid = threadIdx.x;
    const int pp0 = blockIdx.x * 32;
    const int bb = pp0 >> 14;
    const int h  = (pp0 >> 7) & 127;
    const int w0 = pp0 & 127;

    for (int t = tid; t < NROW3 * 32 + 576; t += 512) {
        if (t < NROW3 * 32) {
            const int row = t >> 5, gi = t & 31;
            const int ki = row / 34, kjc = row - ki * 34;
            const int sh = h + ki - 1;
            const int sw = w0 + kjc - 1;
            int4 v = {0, 0, 0, 0};
            if ((unsigned)sh < 128u && (unsigned)sw < 128u)
                v = *(const int4*)&xi_b[(long long)((bb * 128 + sh) * 128 + sw) * 256 + gi * 8];
            *(int4*)&smx[row * XR3 + gi * 8] = v;
        } else {
            const int t2 = t - NROW3 * 32;
            const int p = t2 / 18, rem = t2 - p * 18;
            const int n0 = rem * 8;
            int4 v = *(const int4*)&w_b[((long long)(pp0 + p)) * 144 + n0];
            const unsigned short* u = (const unsigned short*)&v;
            float* d = &smw[p * 148 + n0];
#pragma unroll
            for (int i = 0; i < 8; ++i) d[i] = b2f(u[i]);
        }
    }
    __syncthreads();

    const int g = tid & 15;
    const int p = tid >> 4;

    const int idx0 = g * 144;
    const int kp0  = idx0 >> 8;
    const int c0   = idx0 & 255;
    int len1 = 256 - c0; if (len1 > 144) len1 = 144;
    const int kp1  = kp0 + 1;
    const int base0 = ((kp0 / 3) * 34 + (kp0 % 3) + p) * XR3 + c0;
    const int base1 = (kp1 <= 8) ? (((kp1 / 3) * 34 + (kp1 % 3) + p) * XR3) : 0;

    float wf[9];
#pragma unroll
    for (int kk = 0; kk < 9; ++kk)
        wf[kk] = smw[p * 148 + g * 9 + kk];

    float res[16];
    {
        int4 xv[9];
#pragma unroll
        for (int i = 0; i < 9; ++i) {
            const int e = i * 8;
            const int addr = (e < len1) ? (base0 + e) : (base1 + (e - len1));
            xv[i] = *(const int4*)&smx[addr];
        }
#pragma unroll
        for (int f2 = 0; f2 < 8; ++f2) {
            float a = 0.f;
#pragma unroll
            for (int kk = 0; kk < 9; ++kk) {
                const int e = f2 * 9 + kk;
                const int word = ((const int*)&xv[e >> 3])[(e >> 1) & 3];
                const unsigned short u = (e & 1) ? (unsigned short)(((unsigned)word) >> 16)
                                                 : (unsigned short)(word & 0xffff);
                a += wf[kk] * b2f(u);
            }
            res[f2] = a;
        }
    }
    {
        int4 xv[9];
#pragma unroll
        for (int i = 9; i < 18; ++i) {
            const int e = i * 8;
            const int addr = (e < len1) ? (base0 + e) : (base1 + (e - len1));
            xv[i - 9] = *(const int4*)&smx[addr];
        }
#pragma unroll
        for (int f2 = 8; f2 < 16; ++f2) {
            float a = 0.f;
#pragma unroll
            for (int kk = 0; kk < 9; ++kk) {
                const int e = f2 * 9 + kk;
                const int i = (e >> 3) - 9;
                const int word = ((const int*)&xv[i])[(e >> 1) & 3];
                const unsigned short u = (e & 1) ? (unsigned short)(((unsigned)word) >> 16)
                                                 : (unsigned short)(word & 0xffff);
                a += wf[kk] * b2f(u);
            }
            res[f2] = a;
        }
    }

    const long long orow = ((long long)pp0 + p) * 256 + g * 16;
#pragma unroll
    for (int q = 0; q < 4; ++q) {
        float4 o = {res[q * 4 + 0], res[q * 4 + 1], res[q * 4 + 2], res[q * 4 + 3]};
        *(float4*)&out[orow + q * 4] = o;
    }
}

// ---------------------------------------------------------------------------
extern "C" void kernel_launch(void* const* d_in, const int* in_sizes, int n_in,
                              void* d_out, int out_size, void* d_ws, size_t ws_size,
                              hipStream_t stream) {
    const float* x     = (const float*)d_in[0];
    const float* Wr    = (const float*)d_in[1];
    const float* br    = (const float*)d_in[2];
    const float* gamma = (const float*)d_in[3];
    const float* beta  = (const float*)d_in[4];
    const float* mean  = (const float*)d_in[5];
    const float* var   = (const float*)d_in[6];
    const float* Ws    = (const float*)d_in[7];
    const float* bs    = (const float*)d_in[8];
    const float* Wi    = (const float*)d_in[9];
    const float* bi    = (const float*)d_in[10];
    float* out = (float*)d_out;

    unsigned char* ws = (unsigned char*)d_ws;
    unsigned short* xi_b = (unsigned short*)(ws + 0);            // 33,554,432 B
    unsigned short* w_b  = (unsigned short*)(ws + 33554432);     // 18,874,368 B
    unsigned short* Bt   = (unsigned short*)(ws + 52428800);     //    163,840 B
    unsigned short* Wst  = (unsigned short*)(ws + 52592640);     //     18,432 B

    k_prep<<<dim3(356), dim3(256), 0, stream>>>(Wi, Wr, Ws, Bt, Wst);
    k12<<<dim3(NPIX / 64), dim3(256), 0, stream>>>(
        x, Bt, bi, br, gamma, beta, mean, var, Wst, bs, xi_b, w_b);
    k3_gather<<<dim3(NPIX / 32), dim3(512), 0, stream>>>(xi_b, w_b, out);
}

// Round 5
// 172.705 us; speedup vs baseline: 1.2527x; 1.1987x over previous
//
#include <hip/hip_runtime.h>

#define BN_EPS 1e-3f

typedef __attribute__((ext_vector_type(8))) short bf16x8;
typedef __attribute__((ext_vector_type(4))) float f32x4;

__device__ inline unsigned short f2b(float f) {
    unsigned int u = __float_as_uint(f);
    unsigned int r = (u + 0x7fffu + ((u >> 16) & 1u)) >> 16;
    return (unsigned short)r;
}
__device__ inline float b2f(unsigned short h) {
    return __uint_as_float(((unsigned int)h) << 16);
}

// ---------------------------------------------------------------------------
// k_prep: Bt[n][k] = bf16 of (n<256 ? Wi[k][n] : Wr[k][n-256])   [320,256]
//         Wst[n][k] = bf16 of Ws[k][n]                            [144,64]
// ---------------------------------------------------------------------------
__global__ void k_prep(const float* __restrict__ Wi, const float* __restrict__ Wr,
                       const float* __restrict__ Ws,
                       unsigned short* __restrict__ Bt, unsigned short* __restrict__ Wst) {
    int t = blockIdx.x * 256 + threadIdx.x;
    if (t < 320 * 256) {
        int n = t >> 8, k = t & 255;
        float v = (n < 256) ? Wi[k * 256 + n] : Wr[k * 64 + (n - 256)];
        Bt[t] = f2b(v);
    } else {
        int t2 = t - 320 * 256;
        if (t2 < 144 * 64) {
            int n = t2 >> 6, k = t2 & 63;
            Wst[t2] = f2b(Ws[k * 144 + n]);
        }
    }
}

// ---------------------------------------------------------------------------
// k_fused: one block = one 16x8 output tile (halo 18x10 = 180 px).
//   phase 1 (6 chunks of 32 halo rows, in-place LDS):
//       stage x chunk (fp32->bf16) -> MFMA xi (N=256) + r (N=64) with
//       register-resident B -> epilogue overwrites A rows with xi, r to RS.
//   phase 2: w = r @ Ws^T (+bs) on compacted 128 interior px -> WL.
//   phase 3: verified contiguous-run gather, out fp32.
// LDS (u16): XI 180x264 | RS 180x72 | WL 128x144  = 157,824 B -> 1 block/CU.
// ---------------------------------------------------------------------------
#define XIP 264
#define RS_OFF (180 * XIP)            // 47520
#define RSP 72
#define WL_OFF (RS_OFF + 180 * RSP)   // 60480
#define SMN (WL_OFF + 128 * 144)      // 78912 u16 = 157,824 B

__global__ __launch_bounds__(512, 2) void k_fused(
    const float* __restrict__ x, const unsigned short* __restrict__ Bt,
    const unsigned short* __restrict__ Wst,
    const float* __restrict__ bi, const float* __restrict__ br,
    const float* __restrict__ gamma, const float* __restrict__ beta,
    const float* __restrict__ mean, const float* __restrict__ var,
    const float* __restrict__ bs, float* __restrict__ out)
{
    __shared__ __attribute__((aligned(16))) unsigned short sm[SMN];
    const int tid = threadIdx.x;
    const int bx = blockIdx.x;
    const int w0 = (bx & 7) * 16;
    const int h0 = ((bx >> 3) & 15) * 8;
    const int bb = bx >> 7;

    const int wv = tid >> 6;
    const int lane = tid & 63;
    const int col = lane & 15;
    const int quad = lane >> 4;

    // ---- load per-wave constants & register-resident B fragments ----
    const float bi_v0 = bi[(2 * wv) * 16 + col];
    const float bi_v1 = bi[(2 * wv + 1) * 16 + col];
    const int dcl = (wv & 3) * 16 + col;       // r-column (valid when wv<4)
    const float brd = br[dcl];
    const float md  = mean[dcl];
    const float sc  = gamma[dcl] * rsqrtf(var[dcl] + BN_EPS);
    const float btv = beta[dcl];

    bf16x8 bx0[8], bx1[8], brr[8];
    {
        const unsigned short* p0 = &Bt[((2 * wv) * 16 + col) * 256];
        const unsigned short* p1 = &Bt[((2 * wv + 1) * 16 + col) * 256];
#pragma unroll
        for (int kc = 0; kc < 8; ++kc) {
            bx0[kc] = *(const bf16x8*)&p0[kc * 32 + quad * 8];
            bx1[kc] = *(const bf16x8*)&p1[kc * 32 + quad * 8];
        }
        if (wv < 4) {
            const unsigned short* pr = &Bt[((16 + wv) * 16 + col) * 256];
#pragma unroll
            for (int kc = 0; kc < 8; ++kc)
                brr[kc] = *(const bf16x8*)&pr[kc * 32 + quad * 8];
        }
    }

    // ---- staging helpers (thread covers halo px hp, 16 ch starting (tid&15)*4,
    //      strided by 64 so each global load instruction is 256B-contiguous) ----
    const int chq = (tid & 15) * 4;

    // prologue: stage chunk 0
    float4 vcur[4];
    int hp_cur;
    {
        hp_cur = (tid >> 4);
        int r = hp_cur / 18, cc = hp_cur - r * 18;
        int gh = h0 - 1 + r, gw = w0 - 1 + cc;
        bool ok = (hp_cur < 180) && ((unsigned)gh < 128u) && ((unsigned)gw < 128u);
        if (ok) {
            const float* src = x + (((long long)(bb * 128 + gh)) * 128 + gw) * 256 + chq;
#pragma unroll
            for (int j = 0; j < 4; ++j) vcur[j] = *(const float4*)&src[j * 64];
        } else {
#pragma unroll
            for (int j = 0; j < 4; ++j) vcur[j] = (float4){0.f, 0.f, 0.f, 0.f};
        }
        if (hp_cur < 180) {
#pragma unroll
            for (int j = 0; j < 4; ++j) {
                uint2 pk;
                pk.x = (unsigned)f2b(vcur[j].x) | ((unsigned)f2b(vcur[j].y) << 16);
                pk.y = (unsigned)f2b(vcur[j].z) | ((unsigned)f2b(vcur[j].w) << 16);
                *(uint2*)&sm[hp_cur * XIP + chq + j * 64] = pk;
            }
        }
    }
    __syncthreads();

    // ---- chunk loop ----
    for (int c = 0; c < 6; ++c) {
        // issue global loads for chunk c+1 (overlap with MFMAs below)
        float4 vn[4];
        int hp_n = 192;
        if (c < 5) {
            hp_n = (c + 1) * 32 + (tid >> 4);
            int r = hp_n / 18, cc = hp_n - r * 18;
            int gh = h0 - 1 + r, gw = w0 - 1 + cc;
            bool ok = (hp_n < 180) && ((unsigned)gh < 128u) && ((unsigned)gw < 128u);
            if (ok) {
                const float* src = x + (((long long)(bb * 128 + gh)) * 128 + gw) * 256 + chq;
#pragma unroll
                for (int j = 0; j < 4; ++j) vn[j] = *(const float4*)&src[j * 64];
            } else {
#pragma unroll
                for (int j = 0; j < 4; ++j) vn[j] = (float4){0.f, 0.f, 0.f, 0.f};
            }
        }

        // MFMA chunk c
        f32x4 a00 = {0.f,0.f,0.f,0.f}, a01 = a00, a10 = a00, a11 = a00;
        f32x4 ar0 = a00, ar1 = a00;
        {
            const int rowA0 = (c * 32 + col) * XIP;
            const int rowA1 = (c * 32 + 16 + col) * XIP;
#pragma unroll
            for (int kc = 0; kc < 8; ++kc) {
                const int kb = kc * 32 + quad * 8;
                bf16x8 a0 = *(const bf16x8*)&sm[rowA0 + kb];
                bf16x8 a1 = *(const bf16x8*)&sm[rowA1 + kb];
                a00 = __builtin_amdgcn_mfma_f32_16x16x32_bf16(a0, bx0[kc], a00, 0, 0, 0);
                a10 = __builtin_amdgcn_mfma_f32_16x16x32_bf16(a1, bx0[kc], a10, 0, 0, 0);
                a01 = __builtin_amdgcn_mfma_f32_16x16x32_bf16(a0, bx1[kc], a01, 0, 0, 0);
                a11 = __builtin_amdgcn_mfma_f32_16x16x32_bf16(a1, bx1[kc], a11, 0, 0, 0);
                if (wv < 4) {
                    ar0 = __builtin_amdgcn_mfma_f32_16x16x32_bf16(a0, brr[kc], ar0, 0, 0, 0);
                    ar1 = __builtin_amdgcn_mfma_f32_16x16x32_bf16(a1, brr[kc], ar1, 0, 0, 0);
                }
            }
        }
        __syncthreads();   // all reads of rows_c done

        // write staged A for chunk c+1 (disjoint rows)
        if (c < 5 && hp_n < 180) {
#pragma unroll
            for (int j = 0; j < 4; ++j) {
                uint2 pk;
                pk.x = (unsigned)f2b(vn[j].x) | ((unsigned)f2b(vn[j].y) << 16);
                pk.y = (unsigned)f2b(vn[j].z) | ((unsigned)f2b(vn[j].w) << 16);
                *(uint2*)&sm[hp_n * XIP + chq + j * 64] = pk;
            }
        }

        // epilogue chunk c: xi -> XI rows_c, r -> RS rows_c
        {
            const int n0 = (2 * wv) * 16 + col;
            const int n1 = (2 * wv + 1) * 16 + col;
            const int rb = c * 32 + quad * 4;
#pragma unroll
            for (int rg = 0; rg < 4; ++rg) {
                const int r0 = rb + rg, r1 = rb + 16 + rg;
                if (r0 < 180) {
                    sm[r0 * XIP + n0] = f2b(a00[rg] + bi_v0);
                    sm[r0 * XIP + n1] = f2b(a01[rg] + bi_v1);
                }
                if (r1 < 180) {
                    sm[r1 * XIP + n0] = f2b(a10[rg] + bi_v0);
                    sm[r1 * XIP + n1] = f2b(a11[rg] + bi_v1);
                }
            }
            if (wv < 4) {
#pragma unroll
                for (int rg = 0; rg < 4; ++rg) {
                    const int r0 = rb + rg, r1 = rb + 16 + rg;
                    if (r0 < 180) {
                        float v = (ar0[rg] + brd - md) * sc + btv;
                        sm[RS_OFF + r0 * RSP + dcl] = f2b(fmaxf(v, 0.f));
                    }
                    if (r1 < 180) {
                        float v = (ar1[rg] + brd - md) * sc + btv;
                        sm[RS_OFF + r1 * RSP + dcl] = f2b(fmaxf(v, 0.f));
                    }
                }
            }
        }
        __syncthreads();
    }

    // ---- phase 2: w = r @ Wst^T (+bs) on compacted interior; wave wv -> m-tile wv ----
    {
        f32x4 wacc[9];
#pragma unroll
        for (int j = 0; j < 9; ++j) wacc[j] = (f32x4){0.f, 0.f, 0.f, 0.f};
        // interior px iq = wv*16 + col -> halo row 19 + wv*18 + col
        const int arow = (19 + wv * 18 + col) * RSP;
#pragma unroll
        for (int kc = 0; kc < 2; ++kc) {
            const int kb = kc * 32 + quad * 8;
            bf16x8 ra = *(const bf16x8*)&sm[RS_OFF + arow + kb];
#pragma unroll
            for (int j = 0; j < 9; ++j) {
                bf16x8 wb = *(const bf16x8*)&Wst[(j * 16 + col) * 64 + kb];
                wacc[j] = __builtin_amdgcn_mfma_f32_16x16x32_bf16(ra, wb, wacc[j], 0, 0, 0);
            }
        }
#pragma unroll
        for (int j = 0; j < 9; ++j) {
            const int n = j * 16 + col;
            const float bv = bs[n];
            const int prow = wv * 16 + quad * 4;
#pragma unroll
            for (int rg = 0; rg < 4; ++rg)
                sm[WL_OFF + (prow + rg) * 144 + n] = f2b(wacc[j][rg] + bv);
        }
    }
    __syncthreads();

    // ---- phase 3: gather ----
    {
        const int g = tid & 15;
        const int pb = tid >> 4;               // 0..31

        const int idx0 = g * 144;
        const int kp0  = idx0 >> 8;
        const int c0   = idx0 & 255;           // multiple of 16
        int len1 = 256 - c0; if (len1 > 144) len1 = 144;
        const int kp1  = kp0 + 1;
        const int koff0 = (kp0 / 3) * 18 + (kp0 % 3);
        const int koff1 = (kp1 <= 8) ? ((kp1 / 3) * 18 + (kp1 % 3)) : 0;

#pragma unroll
        for (int jj = 0; jj < 4; ++jj) {
            const int p = pb + 32 * jj;        // interior px 0..127
            const int phb = (p >> 4) * 18 + (p & 15);
            const int base0 = (phb + koff0) * XIP + c0;
            const int base1 = (phb + koff1) * XIP;

            float wf[9];
#pragma unroll
            for (int kk = 0; kk < 9; ++kk)
                wf[kk] = b2f(sm[WL_OFF + p * 144 + g * 9 + kk]);

            float res[16];
            {
                int4 xv[9];
#pragma unroll
                for (int i = 0; i < 9; ++i) {
                    const int e = i * 8;
                    const int addr = (e < len1) ? (base0 + e) : (base1 + (e - len1));
                    xv[i] = *(const int4*)&sm[addr];
                }
#pragma unroll
                for (int f2 = 0; f2 < 8; ++f2) {
                    float a = 0.f;
#pragma unroll
                    for (int kk = 0; kk < 9; ++kk) {
                        const int e = f2 * 9 + kk;
                        const int word = ((const int*)&xv[e >> 3])[(e >> 1) & 3];
                        const unsigned short u = (e & 1) ? (unsigned short)(((unsigned)word) >> 16)
                                                         : (unsigned short)(word & 0xffff);
                        a += wf[kk] * b2f(u);
                    }
                    res[f2] = a;
                }
            }
            {
                int4 xv[9];
#pragma unroll
                for (int i = 9; i < 18; ++i) {
                    const int e = i * 8;
                    const int addr = (e < len1) ? (base0 + e) : (base1 + (e - len1));
                    xv[i - 9] = *(const int4*)&sm[addr];
                }
#pragma unroll
                for (int f2 = 8; f2 < 16; ++f2) {
                    float a = 0.f;
#pragma unroll
                    for (int kk = 0; kk < 9; ++kk) {
                        const int e = f2 * 9 + kk;
                        const int i = (e >> 3) - 9;
                        const int word = ((const int*)&xv[i])[(e >> 1) & 3];
                        const unsigned short u = (e & 1) ? (unsigned short)(((unsigned)word) >> 16)
                                                         : (unsigned short)(word & 0xffff);
                        a += wf[kk] * b2f(u);
                    }
                    res[f2] = a;
                }
            }

            const long long orow =
                (((long long)(bb * 128 + h0 + (p >> 4))) * 128 + (w0 + (p & 15))) * 256 + g * 16;
#pragma unroll
            for (int q = 0; q < 4; ++q) {
                float4 o = {res[q * 4 + 0], res[q * 4 + 1], res[q * 4 + 2], res[q * 4 + 3]};
                *(float4*)&out[orow + q * 4] = o;
            }
        }
    }
}

// ---------------------------------------------------------------------------
extern "C" void kernel_launch(void* const* d_in, const int* in_sizes, int n_in,
                              void* d_out, int out_size, void* d_ws, size_t ws_size,
                              hipStream_t stream) {
    const float* x     = (const float*)d_in[0];
    const float* Wr    = (const float*)d_in[1];
    const float* br    = (const float*)d_in[2];
    const float* gamma = (const float*)d_in[3];
    const float* beta  = (const float*)d_in[4];
    const float* mean  = (const float*)d_in[5];
    const float* var   = (const float*)d_in[6];
    const float* Ws    = (const float*)d_in[7];
    const float* bs    = (const float*)d_in[8];
    const float* Wi    = (const float*)d_in[9];
    const float* bi    = (const float*)d_in[10];
    float* out = (float*)d_out;

    unsigned char* ws = (unsigned char*)d_ws;
    unsigned short* Bt  = (unsigned short*)(ws + 0);        // 320*256*2 = 163,840 B
    unsigned short* Wst = (unsigned short*)(ws + 163840);   // 144*64*2  =  18,432 B

    k_prep<<<dim3(356), dim3(256), 0, stream>>>(Wi, Wr, Ws, Bt, Wst);
    k_fused<<<dim3(512), dim3(512), 0, stream>>>(
        x, Bt, Wst, bi, br, gamma, beta, mean, var, bs, out);
}